// Round 3
// baseline (1053.562 us; speedup 1.0000x reference)
//
#include <hip/hip_runtime.h>

// GuidedAttentionL1Loss on MI355X — round 3.
// R1: same-address atomics serialized main (114us). R2: per-block partial
// slots -> main <40us; profile now dominated by harness d_ws poison fills
// (~40us, 268MB) + d_in restores — fixed overhead. R3: fuse finalize into
// main via last-block-done to drop one launch.
//
// Inputs: 0=logits[B,2] f32, 1=labels[B] i32, 2=attention_weights[T] f32,
//         3=params[P] f32, 4=xpos (recomputed analytically), 5=segment_ids
//         (unused), 6=lengths[B] i32.  Output: [loss, nll] f32.
//
// ws layout: starts[nseg] int at +0; partial[nseg+PARAM_BLOCKS+1] float at
// next 256B boundary; unsigned counter at next 256B boundary after that.

#define TPB 256
#define PARAM_BLOCKS 256

__device__ __forceinline__ float blockReduceSum(float v, float* sm) {
  #pragma unroll
  for (int off = 32; off > 0; off >>= 1) v += __shfl_down(v, off, 64);
  const int lane = threadIdx.x & 63;
  const int wid  = threadIdx.x >> 6;
  if (lane == 0) sm[wid] = v;
  __syncthreads();
  float s = sm[0] + sm[1] + sm[2] + sm[3];
  __syncthreads();
  return s;
}

__device__ __forceinline__ float2 blockReduceSum2(float a, float b, float* sm) {
  #pragma unroll
  for (int off = 32; off > 0; off >>= 1) {
    a += __shfl_down(a, off, 64);
    b += __shfl_down(b, off, 64);
  }
  const int lane = threadIdx.x & 63;
  const int wid  = threadIdx.x >> 6;
  if (lane == 0) { sm[wid] = a; sm[4 + wid] = b; }
  __syncthreads();
  float2 r;
  r.x = sm[0] + sm[1] + sm[2] + sm[3];
  r.y = sm[4] + sm[5] + sm[6] + sm[7];
  __syncthreads();
  return r;
}

// ---------------------------------------------------------------- kernel A --
// Parallel exclusive scan of lengths -> starts; zero the completion counter.
__global__ __launch_bounds__(TPB)
void scan_kernel(const int* __restrict__ lengths, int nseg,
                 int* __restrict__ starts, unsigned* __restrict__ counter) {
  __shared__ int wsum[4];
  const int t = threadIdx.x;
  if (t == 0) *counter = 0u;  // re-zero every call (ws is poisoned 0xAA)
  const int per = (nseg + TPB - 1) / TPB;  // 32 for B=8192
  const int base = t * per;
  int local = 0;
  for (int j = 0; j < per; j++) {
    int idx = base + j;
    if (idx < nseg) local += lengths[idx];
  }
  const int lane = t & 63, wid = t >> 6;
  int incl = local;
  #pragma unroll
  for (int off = 1; off < 64; off <<= 1) {
    int n = __shfl_up(incl, off, 64);
    if (lane >= off) incl += n;
  }
  if (lane == 63) wsum[wid] = incl;
  __syncthreads();
  int wbase = 0;
  for (int i = 0; i < wid; i++) wbase += wsum[i];
  int run = wbase + incl - local;
  for (int j = 0; j < per; j++) {
    int idx = base + j;
    if (idx < nseg) { starts[idx] = run; run += lengths[idx]; }
  }
}

// ------------------------------------------------------------ segment body --
template <int NC>
__device__ __forceinline__ float seg_body(const float4* __restrict__ w4, int start4,
                                          int len, int lab, float* sm) {
  const float inv_len = 1.0f / (float)len;
  float4 wv[NC], rv[NC];
  float aw = 0.0f, axw = 0.0f;
  #pragma unroll
  for (int k = 0; k < NC; k++) {
    const int vi = (k << 8) + threadIdx.x;
    wv[k] = w4[start4 + vi];
    const int i0 = vi << 2;
    aw += wv[k].x + wv[k].y + wv[k].z + wv[k].w;
    axw = fmaf((float)(i0 + 1) * inv_len, wv[k].x, axw);
    axw = fmaf((float)(i0 + 2) * inv_len, wv[k].y, axw);
    axw = fmaf((float)(i0 + 3) * inv_len, wv[k].z, axw);
    axw = fmaf((float)(i0 + 4) * inv_len, wv[k].w, axw);
  }
  const float2 s2 = blockReduceSum2(aw, axw, sm);
  const float mean = s2.y / s2.x;
  const float invstd = (float)len * (lab == 1 ? 1.0f : 0.001f);
  const float rn = 0.39894228040143267f * invstd;  // 1/(std*sqrt(2pi))
  float ar = 0.0f;
  #pragma unroll
  for (int k = 0; k < NC; k++) {
    const int i0 = ((k << 8) + threadIdx.x) << 2;
    float z0 = ((float)(i0 + 1) * inv_len - mean) * invstd;
    float z1 = ((float)(i0 + 2) * inv_len - mean) * invstd;
    float z2 = ((float)(i0 + 3) * inv_len - mean) * invstd;
    float z3 = ((float)(i0 + 4) * inv_len - mean) * invstd;
    rv[k].x = __expf(-0.5f * z0 * z0) * rn;
    rv[k].y = __expf(-0.5f * z1 * z1) * rn;
    rv[k].z = __expf(-0.5f * z2 * z2) * rn;
    rv[k].w = __expf(-0.5f * z3 * z3) * rn;
    ar += rv[k].x + rv[k].y + rv[k].z + rv[k].w;
  }
  const float r_sum = blockReduceSum(ar, sm);
  const float rinv = 1.0f / (r_sum + 1e-6f);
  float ad = 0.0f;
  #pragma unroll
  for (int k = 0; k < NC; k++) {
    float d0 = wv[k].x - rv[k].x * rinv;
    float d1 = wv[k].y - rv[k].y * rinv;
    float d2 = wv[k].z - rv[k].z * rinv;
    float d3 = wv[k].w - rv[k].w * rinv;
    ad = fmaf(d0, d0, ad); ad = fmaf(d1, d1, ad);
    ad = fmaf(d2, d2, ad); ad = fmaf(d3, d3, ad);
  }
  const float dsum = blockReduceSum(ad, sm);
  return dsum * inv_len;
}

// Generic fallback (re-reads w; unused for this dataset's lengths).
__device__ float seg_generic(const float* __restrict__ w, int start, int len,
                             int lab, float* sm) {
  const float inv_len = 1.0f / (float)len;
  float aw = 0.0f, axw = 0.0f;
  for (int i = threadIdx.x; i < len; i += TPB) {
    float wv = w[start + i];
    aw += wv;
    axw = fmaf((float)(i + 1) * inv_len, wv, axw);
  }
  const float2 s2 = blockReduceSum2(aw, axw, sm);
  const float mean = s2.y / s2.x;
  const float invstd = (float)len * (lab == 1 ? 1.0f : 0.001f);
  const float rn = 0.39894228040143267f * invstd;
  float ar = 0.0f;
  for (int i = threadIdx.x; i < len; i += TPB) {
    float z = ((float)(i + 1) * inv_len - mean) * invstd;
    ar += __expf(-0.5f * z * z) * rn;
  }
  const float r_sum = blockReduceSum(ar, sm);
  const float rinv = 1.0f / (r_sum + 1e-6f);
  float ad = 0.0f;
  for (int i = threadIdx.x; i < len; i += TPB) {
    float z = ((float)(i + 1) * inv_len - mean) * invstd;
    float rh = __expf(-0.5f * z * z) * rn;
    float d = w[start + i] - rh * rinv;
    ad = fmaf(d, d, ad);
  }
  const float dsum = blockReduceSum(ad, sm);
  return dsum * inv_len;
}

// ---------------------------------------------------------------- kernel B --
// Fused: per-segment AWP partials, L1(params) partials, NLL partial, and
// last-block-done final reduction (deterministic: fixed-order sum over fully
// written partials regardless of which block finishes last).
__global__ __launch_bounds__(TPB)
void main_kernel(const float* __restrict__ attw, const float* __restrict__ params,
                 const float* __restrict__ logits, const int* __restrict__ labels,
                 const int* __restrict__ lengths, const int* __restrict__ starts,
                 int nseg, int P, float* __restrict__ partial,
                 unsigned* __restrict__ counter, float* __restrict__ out) {
  __shared__ float sm[8];
  __shared__ bool amLast;
  const int b = blockIdx.x;
  if (b < nseg) {
    const int len = lengths[b];
    const int start = starts[b];
    const int lab = labels[b];
    float r;
    if (len == 1024 && (start & 3) == 0)
      r = seg_body<1>((const float4*)attw, start >> 2, len, lab, sm);
    else if (len == 3072 && (start & 3) == 0)
      r = seg_body<3>((const float4*)attw, start >> 2, len, lab, sm);
    else
      r = seg_generic(attw, start, len, lab, sm);
    if (threadIdx.x == 0) partial[b] = r;
  } else if (b < nseg + PARAM_BLOCKS) {
    const int pb = b - nseg;
    const int P4 = P >> 2;
    const float4* p4 = (const float4*)params;
    float a = 0.0f;
    for (int i = pb * TPB + threadIdx.x; i < P4; i += PARAM_BLOCKS * TPB) {
      float4 v = p4[i];
      a += fabsf(v.x) + fabsf(v.y) + fabsf(v.z) + fabsf(v.w);
    }
    if (pb == 0 && threadIdx.x == 0)
      for (int i = P4 << 2; i < P; i++) a += fabsf(params[i]);
    float tot = blockReduceSum(a, sm);
    if (threadIdx.x == 0) partial[b] = tot;
  } else {
    // NLL sum: 2-class log-softmax gather
    float acc = 0.0f;
    for (int s = threadIdx.x; s < nseg; s += TPB) {
      float l0 = logits[2 * s], l1 = logits[2 * s + 1];
      int lab = labels[s];
      float m = fmaxf(l0, l1);
      float lse = m + logf(expf(l0 - m) + expf(l1 - m));
      acc += (lab ? l1 : l0) - lse;
    }
    float tot = blockReduceSum(acc, sm);
    if (threadIdx.x == 0) partial[b] = tot;
  }

  // ---- last-block-done finalize ----
  __threadfence();  // release partial[b] to device scope
  if (threadIdx.x == 0) {
    unsigned old = atomicAdd(counter, 1u);
    amLast = (old == (unsigned)(gridDim.x - 1));
  }
  __syncthreads();
  if (amLast) {
    __threadfence();  // acquire: all partials visible
    float a_awp = 0.0f, a_abs = 0.0f;
    for (int i = threadIdx.x; i < nseg; i += TPB) a_awp += partial[i];
    for (int i = nseg + threadIdx.x; i < nseg + PARAM_BLOCKS; i += TPB)
      a_abs += partial[i];
    const float2 s2 = blockReduceSum2(a_awp, a_abs, sm);
    if (threadIdx.x == 0) {
      const float nll = -partial[nseg + PARAM_BLOCKS] / (float)nseg;
      const float penalty = 0.5f * 1e-4f * s2.y;      // ALPHA/2 * sum|p|
      const float awp = 0.5f * (s2.x / (float)nseg);  // BETA/2 * mean(per_seg)
      out[0] = nll + penalty + awp;
      out[1] = nll;
    }
  }
}

extern "C" void kernel_launch(void* const* d_in, const int* in_sizes, int n_in,
                              void* d_out, int out_size, void* d_ws, size_t ws_size,
                              hipStream_t stream) {
  const float* logits  = (const float*)d_in[0];
  const int*   labels  = (const int*)d_in[1];
  const float* attw    = (const float*)d_in[2];
  const float* params  = (const float*)d_in[3];
  const int*   lengths = (const int*)d_in[6];
  const int nseg = in_sizes[1];
  const int P    = in_sizes[3];

  int* starts = (int*)d_ws;
  size_t poff = ((size_t)nseg * sizeof(int) + 255) & ~(size_t)255;
  float* partial = (float*)((char*)d_ws + poff);
  size_t coff = poff + (((size_t)(nseg + PARAM_BLOCKS + 1) * sizeof(float) + 255)
                        & ~(size_t)255);
  unsigned* counter = (unsigned*)((char*)d_ws + coff);
  float* out = (float*)d_out;

  scan_kernel<<<1, TPB, 0, stream>>>(lengths, nseg, starts, counter);
  main_kernel<<<nseg + PARAM_BLOCKS + 1, TPB, 0, stream>>>(
      attw, params, logits, labels, lengths, starts, nseg, P, partial, counter, out);
}

// Round 4
// 211.332 us; speedup vs baseline: 4.9853x; 4.9853x over previous
//
#include <hip/hip_runtime.h>

// GuidedAttentionL1Loss on MI355X — round 4.
// R1: same-address atomics serialized main (114us). R2: per-block partial
// slots + separate finalize -> 209us total, main <40us. R3 FAILED: last-block
// -done fusion added 2 device-scope __threadfence per block -> L2 writeback
// storm on 8 non-coherent XCD L2s, main 870us. Reverted to R2's 3-launch
// structure (kernel boundary = one amortized flush).
// R4 changes: (a) expand sum((w-r)^2) = sum w^2 - 2*rinv*sum(w*rh)
// + rinv^2*sum(rh^2) -> 2 reduction rounds instead of 4, no rv[] registers;
// (b) wave-per-segment (4 segs / 256-block): shfl_xor butterfly reductions,
// no __syncthreads / LDS in the segment path.
//
// Inputs: 0=logits[B,2] f32, 1=labels[B] i32, 2=attention_weights[T] f32,
//         3=params[P] f32, 4=xpos (recomputed analytically), 5=segment_ids
//         (unused), 6=lengths[B] i32.  Output: [loss, nll] f32.
//
// ws: starts[nseg] int at +0; partial[nseg+PARAM_BLOCKS+1] float at next
// 256B boundary ([0..nseg)=awp, [nseg..nseg+PB)=abs, [nseg+PB]=nll).

#define TPB 256
#define PARAM_BLOCKS 256
#define SEGS_PER_BLOCK 4

__device__ __forceinline__ void waveReduce3(float& a, float& b, float& c) {
  #pragma unroll
  for (int off = 32; off > 0; off >>= 1) {
    a += __shfl_xor(a, off, 64);
    b += __shfl_xor(b, off, 64);
    c += __shfl_xor(c, off, 64);
  }
}

__device__ __forceinline__ float blockReduceSum(float v, float* sm) {
  #pragma unroll
  for (int off = 32; off > 0; off >>= 1) v += __shfl_down(v, off, 64);
  const int lane = threadIdx.x & 63;
  const int wid  = threadIdx.x >> 6;
  if (lane == 0) sm[wid] = v;
  __syncthreads();
  float s = sm[0] + sm[1] + sm[2] + sm[3];
  __syncthreads();
  return s;
}

// ---------------------------------------------------------------- kernel A --
// Parallel exclusive scan of lengths -> starts. One block.
__global__ __launch_bounds__(TPB)
void scan_kernel(const int* __restrict__ lengths, int nseg,
                 int* __restrict__ starts) {
  __shared__ int wsum[4];
  const int t = threadIdx.x;
  const int per = (nseg + TPB - 1) / TPB;  // 32 for B=8192
  const int base = t * per;
  int local = 0;
  for (int j = 0; j < per; j++) {
    int idx = base + j;
    if (idx < nseg) local += lengths[idx];
  }
  const int lane = t & 63, wid = t >> 6;
  int incl = local;
  #pragma unroll
  for (int off = 1; off < 64; off <<= 1) {
    int n = __shfl_up(incl, off, 64);
    if (lane >= off) incl += n;
  }
  if (lane == 63) wsum[wid] = incl;
  __syncthreads();
  int wbase = 0;
  for (int i = 0; i < wid; i++) wbase += wsum[i];
  int run = wbase + incl - local;
  for (int j = 0; j < per; j++) {
    int idx = base + j;
    if (idx < nseg) { starts[idx] = run; run += lengths[idx]; }
  }
}

// ------------------------------------------------------- wave segment body --
// NC float4 chunks per lane: 4 for len=1024, 12 for len=3072.
template <int NC>
__device__ __forceinline__ float seg_wave(const float4* __restrict__ w4,
                                          int start4, int len, int lab) {
  const int lane = threadIdx.x & 63;
  const float inv_len = 1.0f / (float)len;
  float4 wv[NC];
  float aw = 0.0f, axw = 0.0f, aww = 0.0f;
  #pragma unroll
  for (int k = 0; k < NC; k++) {
    const int vi = (k << 6) + lane;  // float4 index within segment
    wv[k] = w4[start4 + vi];
    const int i0 = vi << 2;
    aw += wv[k].x + wv[k].y + wv[k].z + wv[k].w;
    axw = fmaf((float)(i0 + 1) * inv_len, wv[k].x, axw);
    axw = fmaf((float)(i0 + 2) * inv_len, wv[k].y, axw);
    axw = fmaf((float)(i0 + 3) * inv_len, wv[k].z, axw);
    axw = fmaf((float)(i0 + 4) * inv_len, wv[k].w, axw);
    aww = fmaf(wv[k].x, wv[k].x, aww);
    aww = fmaf(wv[k].y, wv[k].y, aww);
    aww = fmaf(wv[k].z, wv[k].z, aww);
    aww = fmaf(wv[k].w, wv[k].w, aww);
  }
  waveReduce3(aw, axw, aww);            // all lanes hold the sums
  const float mean = axw / aw;
  const float invstd = (float)len * (lab == 1 ? 1.0f : 0.001f);
  const float rn = 0.39894228040143267f * invstd;  // 1/(std*sqrt(2pi))
  float ar = 0.0f, awr = 0.0f, arr = 0.0f;
  #pragma unroll
  for (int k = 0; k < NC; k++) {
    const int i0 = ((k << 6) + lane) << 2;
    float z0 = ((float)(i0 + 1) * inv_len - mean) * invstd;
    float z1 = ((float)(i0 + 2) * inv_len - mean) * invstd;
    float z2 = ((float)(i0 + 3) * inv_len - mean) * invstd;
    float z3 = ((float)(i0 + 4) * inv_len - mean) * invstd;
    float r0 = __expf(-0.5f * z0 * z0) * rn;
    float r1 = __expf(-0.5f * z1 * z1) * rn;
    float r2 = __expf(-0.5f * z2 * z2) * rn;
    float r3 = __expf(-0.5f * z3 * z3) * rn;
    ar += r0 + r1 + r2 + r3;
    awr = fmaf(wv[k].x, r0, awr); awr = fmaf(wv[k].y, r1, awr);
    awr = fmaf(wv[k].z, r2, awr); awr = fmaf(wv[k].w, r3, awr);
    arr = fmaf(r0, r0, arr); arr = fmaf(r1, r1, arr);
    arr = fmaf(r2, r2, arr); arr = fmaf(r3, r3, arr);
  }
  waveReduce3(ar, awr, arr);
  const float rinv = 1.0f / (ar + 1e-6f);
  const float dsum = aww - 2.0f * rinv * awr + rinv * rinv * arr;
  return dsum * inv_len;
}

// Generic wave fallback (re-reads w; unused for this dataset's lengths).
__device__ float seg_wave_generic(const float* __restrict__ w, int start,
                                  int len, int lab) {
  const int lane = threadIdx.x & 63;
  const float inv_len = 1.0f / (float)len;
  float aw = 0.0f, axw = 0.0f, aww = 0.0f;
  for (int i = lane; i < len; i += 64) {
    float wv = w[start + i];
    aw += wv;
    axw = fmaf((float)(i + 1) * inv_len, wv, axw);
    aww = fmaf(wv, wv, aww);
  }
  waveReduce3(aw, axw, aww);
  const float mean = axw / aw;
  const float invstd = (float)len * (lab == 1 ? 1.0f : 0.001f);
  const float rn = 0.39894228040143267f * invstd;
  float ar = 0.0f, awr = 0.0f, arr = 0.0f;
  for (int i = lane; i < len; i += 64) {
    float z = ((float)(i + 1) * inv_len - mean) * invstd;
    float rh = __expf(-0.5f * z * z) * rn;
    ar += rh;
    awr = fmaf(w[start + i], rh, awr);
    arr = fmaf(rh, rh, arr);
  }
  waveReduce3(ar, awr, arr);
  const float rinv = 1.0f / (ar + 1e-6f);
  const float dsum = aww - 2.0f * rinv * awr + rinv * rinv * arr;
  return dsum * inv_len;
}

// ---------------------------------------------------------------- kernel B --
__global__ __launch_bounds__(TPB)
void main_kernel(const float* __restrict__ attw, const float* __restrict__ params,
                 const float* __restrict__ logits, const int* __restrict__ labels,
                 const int* __restrict__ lengths, const int* __restrict__ starts,
                 int nseg, int P, float* __restrict__ partial) {
  __shared__ float sm[4];
  const int b = blockIdx.x;
  const int nsegblk = (nseg + SEGS_PER_BLOCK - 1) / SEGS_PER_BLOCK;
  if (b < nsegblk) {
    const int wid = threadIdx.x >> 6;
    const int seg = b * SEGS_PER_BLOCK + wid;
    if (seg < nseg) {
      const int len = lengths[seg];
      const int start = starts[seg];
      const int lab = labels[seg];
      float r;
      if (len == 1024 && (start & 3) == 0)
        r = seg_wave<4>((const float4*)attw, start >> 2, len, lab);
      else if (len == 3072 && (start & 3) == 0)
        r = seg_wave<12>((const float4*)attw, start >> 2, len, lab);
      else
        r = seg_wave_generic(attw, start, len, lab);
      if ((threadIdx.x & 63) == 0) partial[seg] = r;
    }
  } else if (b < nsegblk + PARAM_BLOCKS) {
    const int pb = b - nsegblk;
    const int P4 = P >> 2;
    const float4* p4 = (const float4*)params;
    float a = 0.0f;
    for (int i = pb * TPB + threadIdx.x; i < P4; i += PARAM_BLOCKS * TPB) {
      float4 v = p4[i];
      a += fabsf(v.x) + fabsf(v.y) + fabsf(v.z) + fabsf(v.w);
    }
    if (pb == 0 && threadIdx.x == 0)
      for (int i = P4 << 2; i < P; i++) a += fabsf(params[i]);
    float tot = blockReduceSum(a, sm);
    if (threadIdx.x == 0) partial[nseg + pb] = tot;
  } else {
    // NLL sum: 2-class log-softmax gather
    float acc = 0.0f;
    for (int s = threadIdx.x; s < nseg; s += TPB) {
      float l0 = logits[2 * s], l1 = logits[2 * s + 1];
      int lab = labels[s];
      float m = fmaxf(l0, l1);
      float lse = m + logf(expf(l0 - m) + expf(l1 - m));
      acc += (lab ? l1 : l0) - lse;
    }
    float tot = blockReduceSum(acc, sm);
    if (threadIdx.x == 0) partial[nseg + PARAM_BLOCKS] = tot;
  }
}

// ---------------------------------------------------------------- kernel C --
__global__ __launch_bounds__(TPB)
void finalize_kernel(const float* __restrict__ partial, int nseg,
                     float* __restrict__ out) {
  __shared__ float sm[8];
  float a_awp = 0.0f, a_abs = 0.0f;
  for (int i = threadIdx.x; i < nseg; i += TPB) a_awp += partial[i];
  for (int i = threadIdx.x; i < PARAM_BLOCKS; i += TPB) a_abs += partial[nseg + i];
  // fused 2-value block reduction
  #pragma unroll
  for (int off = 32; off > 0; off >>= 1) {
    a_awp += __shfl_down(a_awp, off, 64);
    a_abs += __shfl_down(a_abs, off, 64);
  }
  const int lane = threadIdx.x & 63, wid = threadIdx.x >> 6;
  if (lane == 0) { sm[wid] = a_awp; sm[4 + wid] = a_abs; }
  __syncthreads();
  if (threadIdx.x == 0) {
    float s_awp = sm[0] + sm[1] + sm[2] + sm[3];
    float s_abs = sm[4] + sm[5] + sm[6] + sm[7];
    const float nll = -partial[nseg + PARAM_BLOCKS] / (float)nseg;
    const float penalty = 0.5f * 1e-4f * s_abs;        // ALPHA/2 * sum|p|
    const float awp = 0.5f * (s_awp / (float)nseg);    // BETA/2 * mean(per_seg)
    out[0] = nll + penalty + awp;
    out[1] = nll;
  }
}

extern "C" void kernel_launch(void* const* d_in, const int* in_sizes, int n_in,
                              void* d_out, int out_size, void* d_ws, size_t ws_size,
                              hipStream_t stream) {
  const float* logits  = (const float*)d_in[0];
  const int*   labels  = (const int*)d_in[1];
  const float* attw    = (const float*)d_in[2];
  const float* params  = (const float*)d_in[3];
  const int*   lengths = (const int*)d_in[6];
  const int nseg = in_sizes[1];
  const int P    = in_sizes[3];

  int* starts = (int*)d_ws;
  size_t poff = ((size_t)nseg * sizeof(int) + 255) & ~(size_t)255;
  float* partial = (float*)((char*)d_ws + poff);
  float* out = (float*)d_out;

  const int nsegblk = (nseg + SEGS_PER_BLOCK - 1) / SEGS_PER_BLOCK;
  scan_kernel<<<1, TPB, 0, stream>>>(lengths, nseg, starts);
  main_kernel<<<nsegblk + PARAM_BLOCKS + 1, TPB, 0, stream>>>(
      attw, params, logits, labels, lengths, starts, nseg, P, partial);
  finalize_kernel<<<1, TPB, 0, stream>>>(partial, nseg, out);
}